// Round 10
// baseline (104.263 us; speedup 1.0000x reference)
//
#include <hip/hip_runtime.h>
#include <hip/hip_bf16.h>

#define F 64
#define R 64
#define O 64
#define BLOCK_B 32   // batch rows per block (256 threads, 4 waves)

typedef short bf16x8 __attribute__((ext_vector_type(8)));
typedef float f32x4 __attribute__((ext_vector_type(4)));
typedef float f32x2 __attribute__((ext_vector_type(2)));

static __device__ __forceinline__ unsigned short f2bf(float f) {
    unsigned u = __builtin_bit_cast(unsigned, f);
    unsigned r = (u + 0x7fffu + ((u >> 16) & 1u)) >> 16;
    return (unsigned short)r;
}

// ---------------------------------------------------------------------------
// Prep kernel (flat, 146 blocks x 256) — proven variant.
//   threads [0, 33280): pack W (fp32) -> Wpk (bf16, MFMA B-fragment order):
//     dst bf16x8 idx = ((nt*65 + f)*2 + kk)*64 + lane
//     elem j = W[o][f*64 + r], o = nt*16+(lane&15), r = (lane>>4)*8 + j + kk*32
//   threads [33280, 37376): prm[u] = {s, mn*s, t, c}, u = f*64 + r
// ---------------------------------------------------------------------------
__global__ __launch_bounds__(256) void fq_prep(
        const float* __restrict__ tt, const float* __restrict__ mean,
        const float* __restrict__ std_, const float* __restrict__ W,
        float* __restrict__ prm, unsigned short* __restrict__ Wpk)
{
    const int tg = blockIdx.x * 256 + threadIdx.x;
    if (tg < 65 * 512) {
        const int f    = tg >> 9;
        const int u8   = tg & 511;
        const int lane = u8 & 63;
        const int kk   = (u8 >> 6) & 1;
        const int nt   = u8 >> 7;
        const int o    = nt * 16 + (lane & 15);
        const int rb   = ((lane >> 4) << 3) + kk * 32;
        const float* src = W + o * 4160 + f * 64 + rb;
        unsigned short v[8];
#pragma unroll
        for (int j = 0; j < 8; ++j) v[j] = f2bf(src[j]);
        const int dst = ((nt * 65 + f) * 2 + kk) * 64 + lane;
        *(bf16x8*)(Wpk + (size_t)dst * 8) = *(bf16x8*)v;
    } else if (tg < 65 * 512 + 4096) {
        const int u = tg - 65 * 512;
        float sd = std_[u];
        float mn = mean[u];
        float th = tanhf(tt[u]);
        float s  = 1.2011224087864498f / sd;  // sqrt(log2(e)) / std
        float4 p;
        p.x = s;
        p.y = mn * s;
        p.z = th;
        p.w = 0.5f * (1.0f - th);
        ((float4*)prm)[u] = p;
    }
}

// ---------------------------------------------------------------------------
// Main fused kernel: block = 32 batch rows, 256 threads (4 waves), 1024 blks.
// Same tiling/state as round 9 per wave (spill-free), but 4 blocks/CU for
// finer cross-block stage1/stage2 overlap. Stage-1 math in f32x2 vector ops
// (__builtin_elementwise_fma) for v_pk_fma_f32/v_pk_mul_f32 codegen.
// Normalization deferred to epilogue; ONE barrier; dist-2 W prefetch.
// wave w = nt (16 cols), 2 row-tiles (rows 16mm+m_in, mm=0,1).
// ---------------------------------------------------------------------------
__global__ __launch_bounds__(256, 4) void fq_main(
        const float* __restrict__ X,
        const float4* __restrict__ prm,
        const bf16x8* __restrict__ Wp,
        float* __restrict__ out)
{
    __shared__ __align__(16) float xt[64][36];              // [f][row]
    __shared__ __align__(16) unsigned short fireb[32][72];  // [row][r] bf16
    __shared__ __align__(16) float rinv[BLOCK_B];

    const int t    = threadIdx.x;
    const int lane = t & 63;
    const int w    = __builtin_amdgcn_readfirstlane(t >> 6);  // wave 0..3 (= nt)
    const int b0   = blockIdx.x * BLOCK_B;
    const int nt   = w;

    // ---- issue X loads + first W prefetch pairs early ----------------------
    const int xrow = t >> 3;          // 0..31
    const int xf8  = (t & 7) * 8;     // 0,8,...,56
    float4 xh0 = *(const float4*)(X + (size_t)(b0 + xrow) * 64 + xf8);
    float4 xh1 = *(const float4*)(X + (size_t)(b0 + xrow) * 64 + xf8 + 4);

    const bf16x8* wpb = Wp + (size_t)(nt * 130) * 64 + lane;
    bf16x8 pe0 = wpb[0 * 64],  pe1 = wpb[1 * 64];     // f = 0
    bf16x8 po0 = wpb[2 * 64],  po1 = wpb[3 * 64];     // f = 1

    // ---- stage 1: firing strengths, rows 8w..8w+7, lane = r ----------------
    {
        f32x2 fire2[4];
#pragma unroll
        for (int i = 0; i < 4; ++i) fire2[i] = (f32x2){1.f, 1.f};
        const float* Xw = X + (size_t)(b0 + 8 * w) * 64;
        float4 p = prm[lane];          // f = 0
#pragma unroll 2
        for (int f = 0; f < F; ++f) {
            const int pf = (f + 1 < 64) ? f + 1 : 63;
            float4 pn = prm[pf * 64 + lane];      // distance-1 prefetch
            f32x2 px = (f32x2){p.x, p.x};
            f32x2 py = (f32x2){-p.y, -p.y};
            f32x2 pt = (f32x2){p.z, p.z};
            f32x2 pc = (f32x2){p.w, p.w};
#pragma unroll
            for (int i = 0; i < 4; ++i) {
                f32x2 x;
                x.x = Xw[(2 * i) * 64 + f];           // wave-uniform -> s_load
                x.y = Xw[(2 * i + 1) * 64 + f];
                f32x2 z  = __builtin_elementwise_fma(x, px, py);   // pk_fma
                f32x2 nz = -(z * z);                               // pk_mul(neg)
                f32x2 g;
                g.x = __builtin_amdgcn_exp2f(nz.x);
                g.y = __builtin_amdgcn_exp2f(nz.y);
                f32x2 m = __builtin_elementwise_fma(g, pt, pc);    // pk_fma
                fire2[i] = fire2[i] * m;                           // pk_mul
            }
            p = pn;
        }
        // write X slab (transposed) + raw-fire bf16 rows
#pragma unroll
        for (int j = 0; j < 4; ++j) {
            xt[xf8 + j][xrow]     = xh0[j];
            xt[xf8 + 4 + j][xrow] = xh1[j];
        }
        const int r0 = 8 * w;
#pragma unroll
        for (int i = 0; i < 4; ++i) {
            fireb[r0 + 2 * i][lane]     = f2bf(fire2[i].x);
            fireb[r0 + 2 * i + 1][lane] = f2bf(fire2[i].y);
        }
        // in-wave butterfly row sums -> rinv
#pragma unroll
        for (int i = 0; i < 4; ++i) {
            float sx = fire2[i].x, sy = fire2[i].y;
#pragma unroll
            for (int d = 1; d < 64; d <<= 1) {
                sx += __shfl_xor(sx, d);
                sy += __shfl_xor(sy, d);
            }
            if (lane == 0) {
                rinv[r0 + 2 * i]     = 1.0f / sx;
                rinv[r0 + 2 * i + 1] = 1.0f / sy;
            }
        }
    }
    __syncthreads();   // the ONE barrier

    // ---- stage 2: 2 row-tiles per wave, dist-2 W prefetch ------------------
    const int m_in = lane & 15;
    const int quad = lane >> 4;
    const int q16  = quad * 16;   // byte offset of quad's 8-bf16 chunk

    bf16x8 wfrag[2][2];   // [mm][kk] — direct reads, raw (unnormalized) fire
#pragma unroll
    for (int mm = 0; mm < 2; ++mm) {
        const int myrow = 16 * mm + m_in;
        wfrag[mm][0] = *(const bf16x8*)((const char*)&fireb[myrow][0] + q16);
        wfrag[mm][1] = *(const bf16x8*)((const char*)&fireb[myrow][32] + q16);
    }

    f32x4 acc[2];
    acc[0] = (f32x4){0.f, 0.f, 0.f, 0.f};
    acc[1] = (f32x4){0.f, 0.f, 0.f, 0.f};
    const f32x4 z4 = (f32x4){0.f, 0.f, 0.f, 0.f};

#pragma unroll 2
    for (int i = 0; i < 32; ++i) {
        const int fe = 2 * i, fo = 2 * i + 1;
        bf16x8 ce0 = pe0, ce1 = pe1, co0 = po0, co1 = po1;
        const int se = (fe + 2 <= 64) ? fe + 2 : 64;   // clamp to bias slab
        const int so = (fo + 2 <= 64) ? fo + 2 : 64;
        pe0 = wpb[(2 * se) * 64];  pe1 = wpb[(2 * se + 1) * 64];
        po0 = wpb[(2 * so) * 64];  po1 = wpb[(2 * so + 1) * 64];
#pragma unroll
        for (int mm = 0; mm < 2; ++mm) {
            f32x4 U = __builtin_amdgcn_mfma_f32_16x16x32_bf16(wfrag[mm][0], ce0, z4, 0, 0, 0);
            U = __builtin_amdgcn_mfma_f32_16x16x32_bf16(wfrag[mm][1], ce1, U, 0, 0, 0);
            f32x4 xv = *(const f32x4*)&xt[fe][16 * mm + quad * 4];
#pragma unroll
            for (int reg = 0; reg < 4; ++reg)
                acc[mm][reg] = __builtin_fmaf(xv[reg], U[reg], acc[mm][reg]);
        }
#pragma unroll
        for (int mm = 0; mm < 2; ++mm) {
            f32x4 U = __builtin_amdgcn_mfma_f32_16x16x32_bf16(wfrag[mm][0], co0, z4, 0, 0, 0);
            U = __builtin_amdgcn_mfma_f32_16x16x32_bf16(wfrag[mm][1], co1, U, 0, 0, 0);
            f32x4 xv = *(const f32x4*)&xt[fo][16 * mm + quad * 4];
#pragma unroll
            for (int reg = 0; reg < 4; ++reg)
                acc[mm][reg] = __builtin_fmaf(xv[reg], U[reg], acc[mm][reg]);
        }
    }

    // bias slab (x = 1): pair resident in pe0/pe1 from the exit prefetch
#pragma unroll
    for (int mm = 0; mm < 2; ++mm) {
        f32x4 U = __builtin_amdgcn_mfma_f32_16x16x32_bf16(wfrag[mm][0], pe0, z4, 0, 0, 0);
        U = __builtin_amdgcn_mfma_f32_16x16x32_bf16(wfrag[mm][1], pe1, U, 0, 0, 0);
#pragma unroll
        for (int reg = 0; reg < 4; ++reg)
            acc[mm][reg] += U[reg];
    }

    // epilogue: out = acc * rinv[row];  C/D: col = lane&15, row = quad*4+reg
#pragma unroll
    for (int mm = 0; mm < 2; ++mm) {
        f32x4 rv = *(const f32x4*)&rinv[16 * mm + quad * 4];
#pragma unroll
        for (int reg = 0; reg < 4; ++reg) {
            const int row = b0 + 16 * mm + quad * 4 + reg;
            out[(size_t)row * 64 + nt * 16 + m_in] = acc[mm][reg] * rv[reg];
        }
    }
}

extern "C" void kernel_launch(void* const* d_in, const int* in_sizes, int n_in,
                              void* d_out, int out_size, void* d_ws, size_t ws_size,
                              hipStream_t stream) {
    const float* X    = (const float*)d_in[0];
    const float* tt   = (const float*)d_in[1];
    const float* mean = (const float*)d_in[2];
    const float* std_ = (const float*)d_in[3];
    const float* W    = (const float*)d_in[4];
    float* out = (float*)d_out;

    // workspace: prm (float4 x 4096 = 64 KiB) | Wpk (bf16 x 65*512*8 = 520 KiB)
    float* prm = (float*)d_ws;
    unsigned short* Wpk = (unsigned short*)((char*)d_ws + 65536);

    fq_prep<<<146, 256, 0, stream>>>(tt, mean, std_, W, prm, Wpk);

    const int nblocks = 32768 / BLOCK_B;  // 1024 blocks x 256 thr = 4096 waves
    fq_main<<<nblocks, 256, 0, stream>>>(X, (const float4*)prm,
                                         (const bf16x8*)Wpk, out);
}